// Round 4
// baseline (435.002 us; speedup 1.0000x reference)
//
#include <hip/hip_runtime.h>

#define N_SRC 50000
#define N_DST1 20000
#define N_DST2 10000
#define E1 320000
#define E2 160000
#define T 12
#define C_IN 64
#define HID 16
#define C_OUT 32

__device__ __forceinline__ float lrelu(float x, float s) { return x > 0.f ? x : s * x; }

// ---------------- Layer-1 transform -----------------------------------
// block = 64 threads = 1 wave; tile = 64 nodes x one t.
// Global loads/stores are lane-contiguous (4 lines/instr); transpose via LDS.
__global__ __launch_bounds__(64) void k_transform1(
    const float* __restrict__ nf, const float* __restrict__ W1,
    const float* __restrict__ a_l, const float* __restrict__ a_r,
    float* __restrict__ hs1, float* __restrict__ el1, float* __restrict__ er1)
{
    __shared__ float xs[64 * 68];   // [node][c] padded stride 68
    __shared__ float wT[16 * 64];   // [o][c]
    int j = threadIdx.x;
    int t = blockIdx.y;
    int n0 = blockIdx.x * 64;
    int nrem = N_SRC - n0; if (nrem > 64) nrem = 64;

    // stage W1 transposed: wT[o*64+c] = W1[c*16+o]
#pragma unroll
    for (int q = 0; q < 16; q++) wT[q * 64 + j] = W1[j * 16 + q];

    // lane-contiguous tile load + transpose into LDS
    const float* gp = nf + ((size_t)t * N_SRC + n0) * 64;
#pragma unroll 16
    for (int k = 0; k < 64; k++) {
        if (k < nrem) xs[k * 68 + j] = gp[k * 64 + j];
    }
    __syncthreads();

    bool act = j < nrem;
    float h[16];
    float el = 0.f, er = 0.f;
    if (act) {
        float4 xq[16];
#pragma unroll
        for (int q = 0; q < 16; q++)
            xq[q] = *reinterpret_cast<const float4*>(&xs[j * 68 + q * 4]);
#pragma unroll
        for (int o = 0; o < 16; o++) {
            const float4* wp = reinterpret_cast<const float4*>(&wT[o * 64]);
            float acc = 0.f;
#pragma unroll
            for (int q = 0; q < 16; q++) {
                float4 w4 = wp[q];
                acc += xq[q].x * w4.x + xq[q].y * w4.y + xq[q].z * w4.z + xq[q].w * w4.w;
            }
            h[o] = acc;
            el += acc * a_l[o];
            er += acc * a_r[o];
        }
    }
    __syncthreads();
    // bounce h through LDS (pad 17) for lane-contiguous global stores
    if (act) {
#pragma unroll
        for (int o = 0; o < 16; o++) xs[j * 17 + o] = h[o];
    }
    __syncthreads();
    float* hg = hs1 + ((size_t)t * N_SRC + n0) * 16;
    int lim = nrem * 16;
#pragma unroll
    for (int q = 0; q < 16; q++) {
        int p = q * 64 + j;
        if (p < lim) hg[p] = xs[(p >> 4) * 17 + (p & 15)];
    }
    if (act) {
        int n = n0 + j;
        el1[(size_t)t * N_SRC + n] = el;
        if (n < N_DST1) er1[(size_t)t * N_DST1 + n] = er;
    }
}

// ---------------- fused CSR build --------------------------------------
__global__ __launch_bounds__(256) void k_hist(
    const int* __restrict__ d1, const int* __restrict__ d2,
    int* __restrict__ cnt1, int* __restrict__ cnt2)
{
    int e = blockIdx.x * 256 + threadIdx.x;
    if (e < E1) atomicAdd(&cnt1[d1[e]], 1);
    else if (e < E1 + E2) atomicAdd(&cnt2[d2[e - E1]], 1);
}

__device__ void scan_one(const int* cnt, int* off, int* cur, int N)
{
    __shared__ int part[256];
    int tx = threadIdx.x;
    int CH = (N + 255) / 256;
    int base = tx * CH;
    int p = 0;
    for (int k = 0; k < CH; k++) { int i = base + k; if (i < N) p += cnt[i]; }
    part[tx] = p;
    __syncthreads();
#pragma unroll
    for (int d = 1; d < 256; d <<= 1) {
        int v = (tx >= d) ? part[tx - d] : 0;
        __syncthreads();
        part[tx] += v;
        __syncthreads();
    }
    int run = (tx == 0) ? 0 : part[tx - 1];
    if (tx == 0) off[0] = 0;
    for (int k = 0; k < CH; k++) {
        int i = base + k;
        if (i < N) { cur[i] = run; run += cnt[i]; off[i + 1] = run; }
    }
}

__global__ __launch_bounds__(256) void k_scan(
    const int* __restrict__ cnt1, int* __restrict__ off1, int* __restrict__ cur1,
    const int* __restrict__ cnt2, int* __restrict__ off2, int* __restrict__ cur2,
    const float* __restrict__ W2, const float* __restrict__ al2,
    const float* __restrict__ ar2, float* __restrict__ wl2, float* __restrict__ wr2)
{
    if (blockIdx.x == 2) {
        int tx = threadIdx.x;
        if (tx < 32) {
            int c = tx & 15;
            const float* a = (tx < 16) ? al2 : ar2;
            float s = 0.f;
            for (int o = 0; o < C_OUT; o++) s += W2[c * C_OUT + o] * a[o];
            if (tx < 16) wl2[c] = s; else wr2[c] = s;
        }
        return;
    }
    if (blockIdx.x == 0) scan_one(cnt1, off1, cur1, N_DST1);
    else                 scan_one(cnt2, off2, cur2, N_DST2);
}

__global__ __launch_bounds__(256) void k_scatter(
    const int* __restrict__ s1, const int* __restrict__ d1, const float* __restrict__ w1,
    int* __restrict__ cur1, int* __restrict__ ss1, float* __restrict__ ws1,
    const int* __restrict__ s2, const int* __restrict__ d2, const float* __restrict__ w2,
    int* __restrict__ cur2, int* __restrict__ ss2, float* __restrict__ ws2)
{
    int e = blockIdx.x * 256 + threadIdx.x;
    if (e < E1) {
        int d = d1[e];
        int p = atomicAdd(&cur1[d], 1);
        ss1[p] = s1[e]; ws1[p] = w1[e];
    } else if (e < E1 + E2) {
        int ee = e - E1;
        int d = d2[ee];
        int p = atomicAdd(&cur2[d], 1);
        ss2[p] = s2[ee]; ws2[p] = w2[ee];
    }
}

// ---------------- fused GAT layer: softmax + aggregate ------------------
// 4 lanes per (d,t) group; o4 = lane's channel quarter.
// FINAL=false: writes h1 (lrelu 0.01) + el2/er2 epilogue (wl=wl2, wr=wr2).
// FINAL=true : applies W2 (wl=W2) + lrelu, writes out[t][d][32].
template <int NDST, int NSRC, bool FINAL>
__global__ __launch_bounds__(256) void k_gat(
    const int* __restrict__ off, const int* __restrict__ s_srt,
    const float* __restrict__ w_srt,
    const float* __restrict__ el, const float* __restrict__ er,
    const float* __restrict__ hs, float* __restrict__ outp,
    const float* __restrict__ wl, const float* __restrict__ wr,
    float* __restrict__ el_out, float* __restrict__ er_out)
{
    int tid = blockIdx.x * 256 + threadIdx.x;
    if (tid >= NDST * T * 4) return;
    int o4 = tid & 3;
    int g = tid >> 2;              // t*NDST + d
    int t = g / NDST;
    int d = g - t * NDST;
    int start = off[d], end = off[d + 1];
    float erv = er[g];
    const float* elb = el + (size_t)t * NSRC;
    const float* hsb = hs + (size_t)t * NSRC * HID;

    // pass 1: max (strided across 4 lanes, then xor-reduce)
    float m = -1e30f;
    for (int i = start + o4; i < end; i += 4)
        m = fmaxf(m, lrelu(elb[s_srt[i]] + erv, 0.2f));
    m = fmaxf(m, __shfl_xor(m, 1));
    m = fmaxf(m, __shfl_xor(m, 2));

    // pass 2: exp + num/den accumulate
    float4 num = make_float4(0.f, 0.f, 0.f, 0.f);
    float den = 0.f;
    for (int i = start; i < end; i++) {
        int s = s_srt[i];
        float ex = __expf(lrelu(elb[s] + erv, 0.2f) - m);
        den += ex;
        float c = ex * w_srt[i];
        float4 hv = *reinterpret_cast<const float4*>(hsb + (size_t)s * HID + o4 * 4);
        num.x += c * hv.x; num.y += c * hv.y; num.z += c * hv.z; num.w += c * hv.w;
    }
    float inv = 1.f / (den + 1e-9f);
    float4 v = make_float4(num.x * inv, num.y * inv, num.z * inv, num.w * inv);

    if (!FINAL) {
        v.x = lrelu(v.x, 0.01f); v.y = lrelu(v.y, 0.01f);
        v.z = lrelu(v.z, 0.01f); v.w = lrelu(v.w, 0.01f);
        *reinterpret_cast<float4*>(outp + (size_t)g * HID + o4 * 4) = v;
        // el2/er2 epilogue: partial dot + 4-lane reduce
        float pl = v.x * wl[o4 * 4] + v.y * wl[o4 * 4 + 1] + v.z * wl[o4 * 4 + 2] + v.w * wl[o4 * 4 + 3];
        float pr = v.x * wr[o4 * 4] + v.y * wr[o4 * 4 + 1] + v.z * wr[o4 * 4 + 2] + v.w * wr[o4 * 4 + 3];
        pl += __shfl_xor(pl, 1); pl += __shfl_xor(pl, 2);
        pr += __shfl_xor(pr, 1); pr += __shfl_xor(pr, 2);
        if (o4 == 0) {
            el_out[g] = pl;
            if (d < N_DST2) er_out[(size_t)t * N_DST2 + d] = pr;
        }
    } else {
        // exchange quarters: lane has quarter o4; pull the other three
        float4 v1, v2, v3;
        v1.x = __shfl_xor(v.x, 1); v1.y = __shfl_xor(v.y, 1); v1.z = __shfl_xor(v.z, 1); v1.w = __shfl_xor(v.w, 1);
        v2.x = __shfl_xor(v.x, 2); v2.y = __shfl_xor(v.y, 2); v2.z = __shfl_xor(v.z, 2); v2.w = __shfl_xor(v.w, 2);
        v3.x = __shfl_xor(v.x, 3); v3.y = __shfl_xor(v.y, 3); v3.z = __shfl_xor(v.z, 3); v3.w = __shfl_xor(v.w, 3);
        int obase = o4 * 8;
        float out8[8];
#pragma unroll
        for (int oo = 0; oo < 8; oo++) out8[oo] = 0.f;
#define ACCQ(Q, R0)                                                             \
        {                                                                       \
            int r0 = (R0) * 4;                                                  \
            _Pragma("unroll")                                                   \
            for (int oo = 0; oo < 8; oo++)                                      \
                out8[oo] += (Q).x * wl[(r0 + 0) * C_OUT + obase + oo]           \
                          + (Q).y * wl[(r0 + 1) * C_OUT + obase + oo]           \
                          + (Q).z * wl[(r0 + 2) * C_OUT + obase + oo]           \
                          + (Q).w * wl[(r0 + 3) * C_OUT + obase + oo];          \
        }
        ACCQ(v,  o4);
        ACCQ(v1, o4 ^ 1);
        ACCQ(v2, o4 ^ 2);
        ACCQ(v3, o4 ^ 3);
#undef ACCQ
        float* op = outp + (size_t)g * C_OUT + obase;
        float4 w0 = make_float4(lrelu(out8[0], 0.01f), lrelu(out8[1], 0.01f),
                                lrelu(out8[2], 0.01f), lrelu(out8[3], 0.01f));
        float4 w1 = make_float4(lrelu(out8[4], 0.01f), lrelu(out8[5], 0.01f),
                                lrelu(out8[6], 0.01f), lrelu(out8[7], 0.01f));
        *reinterpret_cast<float4*>(op) = w0;
        *reinterpret_cast<float4*>(op + 4) = w1;
    }
}

extern "C" void kernel_launch(void* const* d_in, const int* in_sizes, int n_in,
                              void* d_out, int out_size, void* d_ws, size_t ws_size,
                              hipStream_t stream)
{
    const float* node_feat = (const float*)d_in[0];
    const int*   esrc1     = (const int*)d_in[1];
    const int*   edst1     = (const int*)d_in[2];
    const float* ew1       = (const float*)d_in[3];
    const int*   esrc2     = (const int*)d_in[4];
    const int*   edst2     = (const int*)d_in[5];
    const float* ew2       = (const float*)d_in[6];
    const float* W1        = (const float*)d_in[7];
    const float* a_l1      = (const float*)d_in[8];
    const float* a_r1      = (const float*)d_in[9];
    const float* W2        = (const float*)d_in[10];
    const float* a_l2      = (const float*)d_in[11];
    const float* a_r2      = (const float*)d_in[12];
    float* out = (float*)d_out;

    // ---- workspace layout ----
    float* ws = (float*)d_ws;
    float* hs1    = ws;                    // 9,600,000  [T][N_SRC][16]
    float* el1    = hs1 + 9600000;         //   600,000  [T][N_SRC]
    float* er1    = el1 + 600000;          //   240,000  [T][N_DST1]
    float* h1     = er1 + 240000;          // 3,840,000  [T][N_DST1][16]
    float* el2    = h1 + 3840000;          //   240,000  [T][N_DST1]
    float* er2    = el2 + 240000;          //   120,000  [T][N_DST2]
    float* w_srt1 = er2 + 120000;          //   320,000
    float* w_srt2 = w_srt1 + E1;           //   160,000
    float* wl2    = w_srt2 + E2;           //        16
    float* wr2    = wl2 + 16;              //        16
    int* cnt1   = (int*)(wr2 + 16);        //  20,000
    int* cnt2   = cnt1 + N_DST1;           //  10,000  (contiguous with cnt1)
    int* off1   = cnt2 + N_DST2;           //  20,001
    int* cur1   = off1 + N_DST1 + 1;       //  20,000
    int* off2   = cur1 + N_DST1;           //  10,001
    int* cur2   = off2 + N_DST2 + 1;       //  10,000
    int* s_srt1 = cur2 + N_DST2;           // 320,000
    int* s_srt2 = s_srt1 + E1;             // 160,000

    // zero both histograms with ONE memset (adjacent)
    hipMemsetAsync(cnt1, 0, (N_DST1 + N_DST2) * sizeof(int), stream);

    k_hist<<<(E1 + E2 + 255) / 256, 256, 0, stream>>>(edst1, edst2, cnt1, cnt2);
    k_scan<<<3, 256, 0, stream>>>(cnt1, off1, cur1, cnt2, off2, cur2,
                                  W2, a_l2, a_r2, wl2, wr2);
    k_scatter<<<(E1 + E2 + 255) / 256, 256, 0, stream>>>(
        esrc1, edst1, ew1, cur1, s_srt1, w_srt1,
        esrc2, edst2, ew2, cur2, s_srt2, w_srt2);

    {
        dim3 g((N_SRC + 63) / 64, T);
        k_transform1<<<g, 64, 0, stream>>>(node_feat, W1, a_l1, a_r1, hs1, el1, er1);
    }
    k_gat<N_DST1, N_SRC, false><<<(N_DST1 * T * 4 + 255) / 256, 256, 0, stream>>>(
        off1, s_srt1, w_srt1, el1, er1, hs1, h1, wl2, wr2, el2, er2);
    k_gat<N_DST2, N_DST1, true><<<(N_DST2 * T * 4 + 255) / 256, 256, 0, stream>>>(
        off2, s_srt2, w_srt2, el2, er2, h1, out, W2, nullptr, nullptr, nullptr);
}

// Round 5
// 327.242 us; speedup vs baseline: 1.3293x; 1.3293x over previous
//
#include <hip/hip_runtime.h>

#define N_SRC 50000
#define N_DST1 20000
#define N_DST2 10000
#define E1 320000
#define E2 160000
#define T 12
#define C_IN 64
#define HID 16
#define C_OUT 32

__device__ __forceinline__ float lrelu(float x, float s) { return x > 0.f ? x : s * x; }

// ---------------- Layer-1 transform -----------------------------------
// 256 threads = 4 waves; tile = 128 nodes x one t. LDS ~39KB -> 4 blocks/CU.
// Loads and stores lane-contiguous; LDS transpose with <=2-way conflicts.
__global__ __launch_bounds__(256) void k_transform1(
    const float* __restrict__ nf, const float* __restrict__ W1,
    const float* __restrict__ a_l, const float* __restrict__ a_r,
    float* __restrict__ hs1, float* __restrict__ el1, float* __restrict__ er1)
{
    __shared__ float xs[128][68];   // [node][c], stride 68 (272B, 16B-aligned)
    __shared__ float w[C_IN][HID];  // raw W1 copy
    __shared__ float al[HID], ar[HID];
    int tx = threadIdx.x;
    int t = blockIdx.y;
    int n0 = blockIdx.x * 128;
    int nrem = N_SRC - n0; if (nrem > 128) nrem = 128;

    reinterpret_cast<float4*>(&w[0][0])[tx] = reinterpret_cast<const float4*>(W1)[tx];
    if (tx < HID) al[tx] = a_l[tx];
    else if (tx < 2 * HID) ar[tx - HID] = a_r[tx - HID];

    // lane-contiguous tile load (8 x float4 per thread) + transpose into LDS
    const float4* gp = reinterpret_cast<const float4*>(nf + ((size_t)t * N_SRC + n0) * C_IN);
#pragma unroll
    for (int k = 0; k < 8; k++) {
        int f = k * 256 + tx;
        int node = f >> 4;
        if (node < nrem)
            *reinterpret_cast<float4*>(&xs[node][(f & 15) * 4]) = gp[f];
    }
    __syncthreads();

    int q = tx & 3;          // output quarter (4 cols)
    int nn = tx >> 2;        // 0..63 -> nodes nn and nn+64
    float4 accA = make_float4(0.f, 0.f, 0.f, 0.f);
    float4 accB = make_float4(0.f, 0.f, 0.f, 0.f);
#pragma unroll
    for (int c4 = 0; c4 < 16; c4++) {
        float4 xA = *reinterpret_cast<const float4*>(&xs[nn][c4 * 4]);
        float4 xB = *reinterpret_cast<const float4*>(&xs[nn + 64][c4 * 4]);
        float4 w0 = *reinterpret_cast<const float4*>(&w[c4 * 4 + 0][q * 4]);
        float4 w1 = *reinterpret_cast<const float4*>(&w[c4 * 4 + 1][q * 4]);
        float4 w2 = *reinterpret_cast<const float4*>(&w[c4 * 4 + 2][q * 4]);
        float4 w3 = *reinterpret_cast<const float4*>(&w[c4 * 4 + 3][q * 4]);
        accA.x += xA.x * w0.x + xA.y * w1.x + xA.z * w2.x + xA.w * w3.x;
        accA.y += xA.x * w0.y + xA.y * w1.y + xA.z * w2.y + xA.w * w3.y;
        accA.z += xA.x * w0.z + xA.y * w1.z + xA.z * w2.z + xA.w * w3.z;
        accA.w += xA.x * w0.w + xA.y * w1.w + xA.z * w2.w + xA.w * w3.w;
        accB.x += xB.x * w0.x + xB.y * w1.x + xB.z * w2.x + xB.w * w3.x;
        accB.y += xB.x * w0.y + xB.y * w1.y + xB.z * w2.y + xB.w * w3.y;
        accB.z += xB.x * w0.z + xB.y * w1.z + xB.z * w2.z + xB.w * w3.z;
        accB.w += xB.x * w0.w + xB.y * w1.w + xB.z * w2.w + xB.w * w3.w;
    }

    // el/er partials over this lane's 4 outputs, reduce across the 4-lane group
    float alq0 = al[q * 4], alq1 = al[q * 4 + 1], alq2 = al[q * 4 + 2], alq3 = al[q * 4 + 3];
    float arq0 = ar[q * 4], arq1 = ar[q * 4 + 1], arq2 = ar[q * 4 + 2], arq3 = ar[q * 4 + 3];
    float elA = accA.x * alq0 + accA.y * alq1 + accA.z * alq2 + accA.w * alq3;
    float erA = accA.x * arq0 + accA.y * arq1 + accA.z * arq2 + accA.w * arq3;
    float elB = accB.x * alq0 + accB.y * alq1 + accB.z * alq2 + accB.w * alq3;
    float erB = accB.x * arq0 + accB.y * arq1 + accB.z * arq2 + accB.w * arq3;
    elA += __shfl_xor(elA, 1); elA += __shfl_xor(elA, 2);
    erA += __shfl_xor(erA, 1); erA += __shfl_xor(erA, 2);
    elB += __shfl_xor(elB, 1); elB += __shfl_xor(elB, 2);
    erB += __shfl_xor(erB, 1); erB += __shfl_xor(erB, 2);

    // lane-contiguous hs1 stores (thread tx -> float4 #tx, #tx+256)
    float* hb = hs1 + ((size_t)t * N_SRC + n0) * HID;
    if (nn < nrem)
        *reinterpret_cast<float4*>(hb + (size_t)nn * HID + q * 4) = accA;
    if (nn + 64 < nrem)
        *reinterpret_cast<float4*>(hb + (size_t)(nn + 64) * HID + q * 4) = accB;
    if (q == 0) {
        int nA = n0 + nn, nB = nA + 64;
        if (nn < nrem) {
            el1[(size_t)t * N_SRC + nA] = elA;
            if (nA < N_DST1) er1[(size_t)t * N_DST1 + nA] = erA;
        }
        if (nn + 64 < nrem) {
            el1[(size_t)t * N_SRC + nB] = elB;
            if (nB < N_DST1) er1[(size_t)t * N_DST1 + nB] = erB;
        }
    }
}

// ---------------- fused CSR build --------------------------------------
__global__ __launch_bounds__(256) void k_hist(
    const int* __restrict__ d1, const int* __restrict__ d2,
    int* __restrict__ cnt1, int* __restrict__ cnt2)
{
    int e = blockIdx.x * 256 + threadIdx.x;
    if (e < E1) atomicAdd(&cnt1[d1[e]], 1);
    else if (e < E1 + E2) atomicAdd(&cnt2[d2[e - E1]], 1);
}

__device__ void scan_one(const int* cnt, int* off, int* cur, int N)
{
    __shared__ int part[256];
    int tx = threadIdx.x;
    int CH = (N + 255) / 256;
    int base = tx * CH;
    int p = 0;
    for (int k = 0; k < CH; k++) { int i = base + k; if (i < N) p += cnt[i]; }
    part[tx] = p;
    __syncthreads();
#pragma unroll
    for (int d = 1; d < 256; d <<= 1) {
        int v = (tx >= d) ? part[tx - d] : 0;
        __syncthreads();
        part[tx] += v;
        __syncthreads();
    }
    int run = (tx == 0) ? 0 : part[tx - 1];
    if (tx == 0) off[0] = 0;
    for (int k = 0; k < CH; k++) {
        int i = base + k;
        if (i < N) { cur[i] = run; run += cnt[i]; off[i + 1] = run; }
    }
}

__global__ __launch_bounds__(256) void k_scan(
    const int* __restrict__ cnt1, int* __restrict__ off1, int* __restrict__ cur1,
    const int* __restrict__ cnt2, int* __restrict__ off2, int* __restrict__ cur2,
    const float* __restrict__ W2, const float* __restrict__ al2,
    const float* __restrict__ ar2, float* __restrict__ wl2, float* __restrict__ wr2)
{
    if (blockIdx.x == 2) {
        int tx = threadIdx.x;
        if (tx < 32) {
            int c = tx & 15;
            const float* a = (tx < 16) ? al2 : ar2;
            float s = 0.f;
            for (int o = 0; o < C_OUT; o++) s += W2[c * C_OUT + o] * a[o];
            if (tx < 16) wl2[c] = s; else wr2[c] = s;
        }
        return;
    }
    if (blockIdx.x == 0) scan_one(cnt1, off1, cur1, N_DST1);
    else                 scan_one(cnt2, off2, cur2, N_DST2);
}

__global__ __launch_bounds__(256) void k_scatter(
    const int* __restrict__ s1, const int* __restrict__ d1, const float* __restrict__ w1,
    int* __restrict__ cur1, int* __restrict__ ss1, float* __restrict__ ws1,
    const int* __restrict__ s2, const int* __restrict__ d2, const float* __restrict__ w2,
    int* __restrict__ cur2, int* __restrict__ ss2, float* __restrict__ ws2)
{
    int e = blockIdx.x * 256 + threadIdx.x;
    if (e < E1) {
        int d = d1[e];
        int p = atomicAdd(&cur1[d], 1);
        ss1[p] = s1[e]; ws1[p] = w1[e];
    } else if (e < E1 + E2) {
        int ee = e - E1;
        int d = d2[ee];
        int p = atomicAdd(&cur2[d], 1);
        ss2[p] = s2[ee]; ws2[p] = w2[ee];
    }
}

// ---------------- fused GAT layer: softmax + aggregate ------------------
// 4 lanes per (d,t) group; o4 = lane's channel quarter.
// FINAL=false: writes h1 (lrelu 0.01) + el2/er2 epilogue (wl=wl2, wr=wr2).
// FINAL=true : applies W2 (wl=W2) + lrelu, writes out[t][d][32].
template <int NDST, int NSRC, bool FINAL>
__global__ __launch_bounds__(256) void k_gat(
    const int* __restrict__ off, const int* __restrict__ s_srt,
    const float* __restrict__ w_srt,
    const float* __restrict__ el, const float* __restrict__ er,
    const float* __restrict__ hs, float* __restrict__ outp,
    const float* __restrict__ wl, const float* __restrict__ wr,
    float* __restrict__ el_out, float* __restrict__ er_out)
{
    int tid = blockIdx.x * 256 + threadIdx.x;
    if (tid >= NDST * T * 4) return;
    int o4 = tid & 3;
    int g = tid >> 2;              // t*NDST + d
    int t = g / NDST;
    int d = g - t * NDST;
    int start = off[d], end = off[d + 1];
    float erv = er[g];
    const float* elb = el + (size_t)t * NSRC;
    const float* hsb = hs + (size_t)t * NSRC * HID;

    // pass 1: max (strided across 4 lanes, then xor-reduce)
    float m = -1e30f;
    for (int i = start + o4; i < end; i += 4)
        m = fmaxf(m, lrelu(elb[s_srt[i]] + erv, 0.2f));
    m = fmaxf(m, __shfl_xor(m, 1));
    m = fmaxf(m, __shfl_xor(m, 2));

    // pass 2: exp + num/den accumulate
    float4 num = make_float4(0.f, 0.f, 0.f, 0.f);
    float den = 0.f;
    for (int i = start; i < end; i++) {
        int s = s_srt[i];
        float ex = __expf(lrelu(elb[s] + erv, 0.2f) - m);
        den += ex;
        float c = ex * w_srt[i];
        float4 hv = *reinterpret_cast<const float4*>(hsb + (size_t)s * HID + o4 * 4);
        num.x += c * hv.x; num.y += c * hv.y; num.z += c * hv.z; num.w += c * hv.w;
    }
    float inv = 1.f / (den + 1e-9f);
    float4 v = make_float4(num.x * inv, num.y * inv, num.z * inv, num.w * inv);

    if (!FINAL) {
        v.x = lrelu(v.x, 0.01f); v.y = lrelu(v.y, 0.01f);
        v.z = lrelu(v.z, 0.01f); v.w = lrelu(v.w, 0.01f);
        *reinterpret_cast<float4*>(outp + (size_t)g * HID + o4 * 4) = v;
        // el2/er2 epilogue: partial dot + 4-lane reduce
        float pl = v.x * wl[o4 * 4] + v.y * wl[o4 * 4 + 1] + v.z * wl[o4 * 4 + 2] + v.w * wl[o4 * 4 + 3];
        float pr = v.x * wr[o4 * 4] + v.y * wr[o4 * 4 + 1] + v.z * wr[o4 * 4 + 2] + v.w * wr[o4 * 4 + 3];
        pl += __shfl_xor(pl, 1); pl += __shfl_xor(pl, 2);
        pr += __shfl_xor(pr, 1); pr += __shfl_xor(pr, 2);
        if (o4 == 0) {
            el_out[g] = pl;
            if (d < N_DST2) er_out[(size_t)t * N_DST2 + d] = pr;
        }
    } else {
        // exchange quarters: lane has quarter o4; pull the other three
        float4 v1, v2, v3;
        v1.x = __shfl_xor(v.x, 1); v1.y = __shfl_xor(v.y, 1); v1.z = __shfl_xor(v.z, 1); v1.w = __shfl_xor(v.w, 1);
        v2.x = __shfl_xor(v.x, 2); v2.y = __shfl_xor(v.y, 2); v2.z = __shfl_xor(v.z, 2); v2.w = __shfl_xor(v.w, 2);
        v3.x = __shfl_xor(v.x, 3); v3.y = __shfl_xor(v.y, 3); v3.z = __shfl_xor(v.z, 3); v3.w = __shfl_xor(v.w, 3);
        int obase = o4 * 8;
        float out8[8];
#pragma unroll
        for (int oo = 0; oo < 8; oo++) out8[oo] = 0.f;
#define ACCQ(Q, R0)                                                             \
        {                                                                       \
            int r0 = (R0) * 4;                                                  \
            _Pragma("unroll")                                                   \
            for (int oo = 0; oo < 8; oo++)                                      \
                out8[oo] += (Q).x * wl[(r0 + 0) * C_OUT + obase + oo]           \
                          + (Q).y * wl[(r0 + 1) * C_OUT + obase + oo]           \
                          + (Q).z * wl[(r0 + 2) * C_OUT + obase + oo]           \
                          + (Q).w * wl[(r0 + 3) * C_OUT + obase + oo];          \
        }
        ACCQ(v,  o4);
        ACCQ(v1, o4 ^ 1);
        ACCQ(v2, o4 ^ 2);
        ACCQ(v3, o4 ^ 3);
#undef ACCQ
        float* op = outp + (size_t)g * C_OUT + obase;
        float4 w0 = make_float4(lrelu(out8[0], 0.01f), lrelu(out8[1], 0.01f),
                                lrelu(out8[2], 0.01f), lrelu(out8[3], 0.01f));
        float4 w1 = make_float4(lrelu(out8[4], 0.01f), lrelu(out8[5], 0.01f),
                                lrelu(out8[6], 0.01f), lrelu(out8[7], 0.01f));
        *reinterpret_cast<float4*>(op) = w0;
        *reinterpret_cast<float4*>(op + 4) = w1;
    }
}

extern "C" void kernel_launch(void* const* d_in, const int* in_sizes, int n_in,
                              void* d_out, int out_size, void* d_ws, size_t ws_size,
                              hipStream_t stream)
{
    const float* node_feat = (const float*)d_in[0];
    const int*   esrc1     = (const int*)d_in[1];
    const int*   edst1     = (const int*)d_in[2];
    const float* ew1       = (const float*)d_in[3];
    const int*   esrc2     = (const int*)d_in[4];
    const int*   edst2     = (const int*)d_in[5];
    const float* ew2       = (const float*)d_in[6];
    const float* W1        = (const float*)d_in[7];
    const float* a_l1      = (const float*)d_in[8];
    const float* a_r1      = (const float*)d_in[9];
    const float* W2        = (const float*)d_in[10];
    const float* a_l2      = (const float*)d_in[11];
    const float* a_r2      = (const float*)d_in[12];
    float* out = (float*)d_out;

    // ---- workspace layout ----
    float* ws = (float*)d_ws;
    float* hs1    = ws;                    // 9,600,000  [T][N_SRC][16]
    float* el1    = hs1 + 9600000;         //   600,000  [T][N_SRC]
    float* er1    = el1 + 600000;          //   240,000  [T][N_DST1]
    float* h1     = er1 + 240000;          // 3,840,000  [T][N_DST1][16]
    float* el2    = h1 + 3840000;          //   240,000  [T][N_DST1]
    float* er2    = el2 + 240000;          //   120,000  [T][N_DST2]
    float* w_srt1 = er2 + 120000;          //   320,000
    float* w_srt2 = w_srt1 + E1;           //   160,000
    float* wl2    = w_srt2 + E2;           //        16
    float* wr2    = wl2 + 16;              //        16
    int* cnt1   = (int*)(wr2 + 16);        //  20,000
    int* cnt2   = cnt1 + N_DST1;           //  10,000  (contiguous with cnt1)
    int* off1   = cnt2 + N_DST2;           //  20,001
    int* cur1   = off1 + N_DST1 + 1;       //  20,000
    int* off2   = cur1 + N_DST1;           //  10,001
    int* cur2   = off2 + N_DST2 + 1;       //  10,000
    int* s_srt1 = cur2 + N_DST2;           // 320,000
    int* s_srt2 = s_srt1 + E1;             // 160,000

    // zero both histograms with ONE memset (adjacent)
    hipMemsetAsync(cnt1, 0, (N_DST1 + N_DST2) * sizeof(int), stream);

    k_hist<<<(E1 + E2 + 255) / 256, 256, 0, stream>>>(edst1, edst2, cnt1, cnt2);
    k_scan<<<3, 256, 0, stream>>>(cnt1, off1, cur1, cnt2, off2, cur2,
                                  W2, a_l2, a_r2, wl2, wr2);
    k_scatter<<<(E1 + E2 + 255) / 256, 256, 0, stream>>>(
        esrc1, edst1, ew1, cur1, s_srt1, w_srt1,
        esrc2, edst2, ew2, cur2, s_srt2, w_srt2);

    {
        dim3 g((N_SRC + 127) / 128, T);
        k_transform1<<<g, 256, 0, stream>>>(node_feat, W1, a_l1, a_r1, hs1, el1, er1);
    }
    k_gat<N_DST1, N_SRC, false><<<(N_DST1 * T * 4 + 255) / 256, 256, 0, stream>>>(
        off1, s_srt1, w_srt1, el1, er1, hs1, h1, wl2, wr2, el2, er2);
    k_gat<N_DST2, N_DST1, true><<<(N_DST2 * T * 4 + 255) / 256, 256, 0, stream>>>(
        off2, s_srt2, w_srt2, el2, er2, h1, out, W2, nullptr, nullptr, nullptr);
}

// Round 6
// 303.062 us; speedup vs baseline: 1.4354x; 1.0798x over previous
//
#include <hip/hip_runtime.h>

#define N_SRC 50000
#define N_DST1 20000
#define N_DST2 10000
#define E1 320000
#define E2 160000
#define T 12
#define C_IN 64
#define HID 16
#define C_OUT 32

__device__ __forceinline__ float lrelu(float x, float s) { return x > 0.f ? x : s * x; }

// Bijective XCD-aware swizzle (m204 variant): physical block p -> logical w
// such that XCD x = p%8 owns a contiguous chunk of logical work space.
__device__ __forceinline__ int xcd_swizzle(int p, int W) {
    int x = p & 7, k = p >> 3;
    int q = W >> 3, r = W & 7;
    return (x < r ? x * (q + 1) : r * (q + 1) + (x - r) * q) + k;
}

// ---------------- Layer-1 transform -----------------------------------
// 256 threads = 4 waves; tile = 128 nodes x one t. LDS ~39KB -> 4 blocks/CU.
__global__ __launch_bounds__(256) void k_transform1(
    const float* __restrict__ nf, const float* __restrict__ W1,
    const float* __restrict__ a_l, const float* __restrict__ a_r,
    float* __restrict__ hs1, float* __restrict__ el1, float* __restrict__ er1)
{
    __shared__ float xs[128][68];
    __shared__ float w[C_IN][HID];
    __shared__ float al[HID], ar[HID];
    int tx = threadIdx.x;
    int t = blockIdx.y;
    int n0 = blockIdx.x * 128;
    int nrem = N_SRC - n0; if (nrem > 128) nrem = 128;

    reinterpret_cast<float4*>(&w[0][0])[tx] = reinterpret_cast<const float4*>(W1)[tx];
    if (tx < HID) al[tx] = a_l[tx];
    else if (tx < 2 * HID) ar[tx - HID] = a_r[tx - HID];

    const float4* gp = reinterpret_cast<const float4*>(nf + ((size_t)t * N_SRC + n0) * C_IN);
#pragma unroll
    for (int k = 0; k < 8; k++) {
        int f = k * 256 + tx;
        int node = f >> 4;
        if (node < nrem)
            *reinterpret_cast<float4*>(&xs[node][(f & 15) * 4]) = gp[f];
    }
    __syncthreads();

    int q = tx & 3;
    int nn = tx >> 2;
    float4 accA = make_float4(0.f, 0.f, 0.f, 0.f);
    float4 accB = make_float4(0.f, 0.f, 0.f, 0.f);
#pragma unroll
    for (int c4 = 0; c4 < 16; c4++) {
        float4 xA = *reinterpret_cast<const float4*>(&xs[nn][c4 * 4]);
        float4 xB = *reinterpret_cast<const float4*>(&xs[nn + 64][c4 * 4]);
        float4 w0 = *reinterpret_cast<const float4*>(&w[c4 * 4 + 0][q * 4]);
        float4 w1 = *reinterpret_cast<const float4*>(&w[c4 * 4 + 1][q * 4]);
        float4 w2 = *reinterpret_cast<const float4*>(&w[c4 * 4 + 2][q * 4]);
        float4 w3 = *reinterpret_cast<const float4*>(&w[c4 * 4 + 3][q * 4]);
        accA.x += xA.x * w0.x + xA.y * w1.x + xA.z * w2.x + xA.w * w3.x;
        accA.y += xA.x * w0.y + xA.y * w1.y + xA.z * w2.y + xA.w * w3.y;
        accA.z += xA.x * w0.z + xA.y * w1.z + xA.z * w2.z + xA.w * w3.z;
        accA.w += xA.x * w0.w + xA.y * w1.w + xA.z * w2.w + xA.w * w3.w;
        accB.x += xB.x * w0.x + xB.y * w1.x + xB.z * w2.x + xB.w * w3.x;
        accB.y += xB.x * w0.y + xB.y * w1.y + xB.z * w2.y + xB.w * w3.y;
        accB.z += xB.x * w0.z + xB.y * w1.z + xB.z * w2.z + xB.w * w3.z;
        accB.w += xB.x * w0.w + xB.y * w1.w + xB.z * w2.w + xB.w * w3.w;
    }

    float alq0 = al[q * 4], alq1 = al[q * 4 + 1], alq2 = al[q * 4 + 2], alq3 = al[q * 4 + 3];
    float arq0 = ar[q * 4], arq1 = ar[q * 4 + 1], arq2 = ar[q * 4 + 2], arq3 = ar[q * 4 + 3];
    float elA = accA.x * alq0 + accA.y * alq1 + accA.z * alq2 + accA.w * alq3;
    float erA = accA.x * arq0 + accA.y * arq1 + accA.z * arq2 + accA.w * arq3;
    float elB = accB.x * alq0 + accB.y * alq1 + accB.z * alq2 + accB.w * alq3;
    float erB = accB.x * arq0 + accB.y * arq1 + accB.z * arq2 + accB.w * arq3;
    elA += __shfl_xor(elA, 1); elA += __shfl_xor(elA, 2);
    erA += __shfl_xor(erA, 1); erA += __shfl_xor(erA, 2);
    elB += __shfl_xor(elB, 1); elB += __shfl_xor(elB, 2);
    erB += __shfl_xor(erB, 1); erB += __shfl_xor(erB, 2);

    float* hb = hs1 + ((size_t)t * N_SRC + n0) * HID;
    if (nn < nrem)
        *reinterpret_cast<float4*>(hb + (size_t)nn * HID + q * 4) = accA;
    if (nn + 64 < nrem)
        *reinterpret_cast<float4*>(hb + (size_t)(nn + 64) * HID + q * 4) = accB;
    if (q == 0) {
        int nA = n0 + nn, nB = nA + 64;
        if (nn < nrem) {
            el1[(size_t)t * N_SRC + nA] = elA;
            if (nA < N_DST1) er1[(size_t)t * N_DST1 + nA] = erA;
        }
        if (nn + 64 < nrem) {
            el1[(size_t)t * N_SRC + nB] = elB;
            if (nB < N_DST1) er1[(size_t)t * N_DST1 + nB] = erB;
        }
    }
}

// ---------------- fused CSR build --------------------------------------
__global__ __launch_bounds__(256) void k_hist(
    const int* __restrict__ d1, const int* __restrict__ d2,
    int* __restrict__ cnt1, int* __restrict__ cnt2)
{
    int e = blockIdx.x * 256 + threadIdx.x;
    if (e < E1) atomicAdd(&cnt1[d1[e]], 1);
    else if (e < E1 + E2) atomicAdd(&cnt2[d2[e - E1]], 1);
}

__device__ void scan_one(const int* cnt, int* off, int* cur, int N)
{
    __shared__ int part[256];
    int tx = threadIdx.x;
    int CH = (N + 255) / 256;
    int base = tx * CH;
    int p = 0;
    for (int k = 0; k < CH; k++) { int i = base + k; if (i < N) p += cnt[i]; }
    part[tx] = p;
    __syncthreads();
#pragma unroll
    for (int d = 1; d < 256; d <<= 1) {
        int v = (tx >= d) ? part[tx - d] : 0;
        __syncthreads();
        part[tx] += v;
        __syncthreads();
    }
    int run = (tx == 0) ? 0 : part[tx - 1];
    if (tx == 0) off[0] = 0;
    for (int k = 0; k < CH; k++) {
        int i = base + k;
        if (i < N) { cur[i] = run; run += cnt[i]; off[i + 1] = run; }
    }
}

__global__ __launch_bounds__(256) void k_scan(
    const int* __restrict__ cnt1, int* __restrict__ off1, int* __restrict__ cur1,
    const int* __restrict__ cnt2, int* __restrict__ off2, int* __restrict__ cur2,
    const float* __restrict__ W2, const float* __restrict__ al2,
    const float* __restrict__ ar2, float* __restrict__ wl2, float* __restrict__ wr2)
{
    if (blockIdx.x == 2) {
        int tx = threadIdx.x;
        if (tx < 32) {
            int c = tx & 15;
            const float* a = (tx < 16) ? al2 : ar2;
            float s = 0.f;
            for (int o = 0; o < C_OUT; o++) s += W2[c * C_OUT + o] * a[o];
            if (tx < 16) wl2[c] = s; else wr2[c] = s;
        }
        return;
    }
    if (blockIdx.x == 0) scan_one(cnt1, off1, cur1, N_DST1);
    else                 scan_one(cnt2, off2, cur2, N_DST2);
}

__global__ __launch_bounds__(256) void k_scatter(
    const int* __restrict__ s1, const int* __restrict__ d1, const float* __restrict__ w1,
    int* __restrict__ cur1, int* __restrict__ ss1, float* __restrict__ ws1,
    const int* __restrict__ s2, const int* __restrict__ d2, const float* __restrict__ w2,
    int* __restrict__ cur2, int* __restrict__ ss2, float* __restrict__ ws2)
{
    int e = blockIdx.x * 256 + threadIdx.x;
    if (e < E1) {
        int d = d1[e];
        int p = atomicAdd(&cur1[d], 1);
        ss1[p] = s1[e]; ws1[p] = w1[e];
    } else if (e < E1 + E2) {
        int ee = e - E1;
        int d = d2[ee];
        int p = atomicAdd(&cur2[d], 1);
        ss2[p] = s2[ee]; ws2[p] = w2[ee];
    }
}

// ---------------- fused GAT layer: softmax + aggregate ------------------
// 4 lanes per (d,t) group; XCD-swizzled so each XCD's L2 holds ~1.5 t-slices.
template <int NDST, int NSRC, bool FINAL>
__global__ __launch_bounds__(256) void k_gat(
    const int* __restrict__ off, const int* __restrict__ s_srt,
    const float* __restrict__ w_srt,
    const float* __restrict__ el, const float* __restrict__ er,
    const float* __restrict__ hs, float* __restrict__ outp,
    const float* __restrict__ wl, const float* __restrict__ wr,
    float* __restrict__ el_out, float* __restrict__ er_out)
{
    int wblk = xcd_swizzle(blockIdx.x, (NDST * T * 4) / 256);
    int tid = wblk * 256 + threadIdx.x;
    int o4 = tid & 3;
    int g = tid >> 2;              // t*NDST + d
    int t = g / NDST;
    int d = g - t * NDST;
    int start = off[d], end = off[d + 1];
    float erv = er[g];
    const float* elb = el + (size_t)t * NSRC;
    const float* hsb = hs + (size_t)t * NSRC * HID;

    // pass 1: max (strided across 4 lanes, then xor-reduce)
    float m = -1e30f;
    for (int i = start + o4; i < end; i += 4)
        m = fmaxf(m, lrelu(elb[s_srt[i]] + erv, 0.2f));
    m = fmaxf(m, __shfl_xor(m, 1));
    m = fmaxf(m, __shfl_xor(m, 2));

    // pass 2: exp + num/den accumulate
    float4 num = make_float4(0.f, 0.f, 0.f, 0.f);
    float den = 0.f;
    for (int i = start; i < end; i++) {
        int s = s_srt[i];
        float ex = __expf(lrelu(elb[s] + erv, 0.2f) - m);
        den += ex;
        float c = ex * w_srt[i];
        float4 hv = *reinterpret_cast<const float4*>(hsb + (size_t)s * HID + o4 * 4);
        num.x += c * hv.x; num.y += c * hv.y; num.z += c * hv.z; num.w += c * hv.w;
    }
    float inv = 1.f / (den + 1e-9f);
    float4 v = make_float4(num.x * inv, num.y * inv, num.z * inv, num.w * inv);

    if (!FINAL) {
        v.x = lrelu(v.x, 0.01f); v.y = lrelu(v.y, 0.01f);
        v.z = lrelu(v.z, 0.01f); v.w = lrelu(v.w, 0.01f);
        *reinterpret_cast<float4*>(outp + (size_t)g * HID + o4 * 4) = v;
        float pl = v.x * wl[o4 * 4] + v.y * wl[o4 * 4 + 1] + v.z * wl[o4 * 4 + 2] + v.w * wl[o4 * 4 + 3];
        float pr = v.x * wr[o4 * 4] + v.y * wr[o4 * 4 + 1] + v.z * wr[o4 * 4 + 2] + v.w * wr[o4 * 4 + 3];
        pl += __shfl_xor(pl, 1); pl += __shfl_xor(pl, 2);
        pr += __shfl_xor(pr, 1); pr += __shfl_xor(pr, 2);
        if (o4 == 0) {
            el_out[g] = pl;
            if (d < N_DST2) er_out[(size_t)t * N_DST2 + d] = pr;
        }
    } else {
        float4 v1, v2, v3;
        v1.x = __shfl_xor(v.x, 1); v1.y = __shfl_xor(v.y, 1); v1.z = __shfl_xor(v.z, 1); v1.w = __shfl_xor(v.w, 1);
        v2.x = __shfl_xor(v.x, 2); v2.y = __shfl_xor(v.y, 2); v2.z = __shfl_xor(v.z, 2); v2.w = __shfl_xor(v.w, 2);
        v3.x = __shfl_xor(v.x, 3); v3.y = __shfl_xor(v.y, 3); v3.z = __shfl_xor(v.z, 3); v3.w = __shfl_xor(v.w, 3);
        int obase = o4 * 8;
        float out8[8];
#pragma unroll
        for (int oo = 0; oo < 8; oo++) out8[oo] = 0.f;
#define ACCQ(Q, R0)                                                             \
        {                                                                       \
            int r0 = (R0) * 4;                                                  \
            _Pragma("unroll")                                                   \
            for (int oo = 0; oo < 8; oo++)                                      \
                out8[oo] += (Q).x * wl[(r0 + 0) * C_OUT + obase + oo]           \
                          + (Q).y * wl[(r0 + 1) * C_OUT + obase + oo]           \
                          + (Q).z * wl[(r0 + 2) * C_OUT + obase + oo]           \
                          + (Q).w * wl[(r0 + 3) * C_OUT + obase + oo];          \
        }
        ACCQ(v,  o4);
        ACCQ(v1, o4 ^ 1);
        ACCQ(v2, o4 ^ 2);
        ACCQ(v3, o4 ^ 3);
#undef ACCQ
        float* op = outp + (size_t)g * C_OUT + obase;
        float4 w0 = make_float4(lrelu(out8[0], 0.01f), lrelu(out8[1], 0.01f),
                                lrelu(out8[2], 0.01f), lrelu(out8[3], 0.01f));
        float4 w1 = make_float4(lrelu(out8[4], 0.01f), lrelu(out8[5], 0.01f),
                                lrelu(out8[6], 0.01f), lrelu(out8[7], 0.01f));
        *reinterpret_cast<float4*>(op) = w0;
        *reinterpret_cast<float4*>(op + 4) = w1;
    }
}

extern "C" void kernel_launch(void* const* d_in, const int* in_sizes, int n_in,
                              void* d_out, int out_size, void* d_ws, size_t ws_size,
                              hipStream_t stream)
{
    const float* node_feat = (const float*)d_in[0];
    const int*   esrc1     = (const int*)d_in[1];
    const int*   edst1     = (const int*)d_in[2];
    const float* ew1       = (const float*)d_in[3];
    const int*   esrc2     = (const int*)d_in[4];
    const int*   edst2     = (const int*)d_in[5];
    const float* ew2       = (const float*)d_in[6];
    const float* W1        = (const float*)d_in[7];
    const float* a_l1      = (const float*)d_in[8];
    const float* a_r1      = (const float*)d_in[9];
    const float* W2        = (const float*)d_in[10];
    const float* a_l2      = (const float*)d_in[11];
    const float* a_r2      = (const float*)d_in[12];
    float* out = (float*)d_out;

    float* ws = (float*)d_ws;
    float* hs1    = ws;                    // 9,600,000  [T][N_SRC][16]
    float* el1    = hs1 + 9600000;         //   600,000  [T][N_SRC]
    float* er1    = el1 + 600000;          //   240,000  [T][N_DST1]
    float* h1     = er1 + 240000;          // 3,840,000  [T][N_DST1][16]
    float* el2    = h1 + 3840000;          //   240,000  [T][N_DST1]
    float* er2    = el2 + 240000;          //   120,000  [T][N_DST2]
    float* w_srt1 = er2 + 120000;          //   320,000
    float* w_srt2 = w_srt1 + E1;           //   160,000
    float* wl2    = w_srt2 + E2;           //        16
    float* wr2    = wl2 + 16;              //        16
    int* cnt1   = (int*)(wr2 + 16);        //  20,000
    int* cnt2   = cnt1 + N_DST1;           //  10,000
    int* off1   = cnt2 + N_DST2;           //  20,001
    int* cur1   = off1 + N_DST1 + 1;       //  20,000
    int* off2   = cur1 + N_DST1;           //  10,001
    int* cur2   = off2 + N_DST2 + 1;       //  10,000
    int* s_srt1 = cur2 + N_DST2;           // 320,000
    int* s_srt2 = s_srt1 + E1;             // 160,000

    hipMemsetAsync(cnt1, 0, (N_DST1 + N_DST2) * sizeof(int), stream);

    k_hist<<<(E1 + E2 + 255) / 256, 256, 0, stream>>>(edst1, edst2, cnt1, cnt2);
    k_scan<<<3, 256, 0, stream>>>(cnt1, off1, cur1, cnt2, off2, cur2,
                                  W2, a_l2, a_r2, wl2, wr2);
    k_scatter<<<(E1 + E2 + 255) / 256, 256, 0, stream>>>(
        esrc1, edst1, ew1, cur1, s_srt1, w_srt1,
        esrc2, edst2, ew2, cur2, s_srt2, w_srt2);

    {
        dim3 g((N_SRC + 127) / 128, T);
        k_transform1<<<g, 256, 0, stream>>>(node_feat, W1, a_l1, a_r1, hs1, el1, er1);
    }
    k_gat<N_DST1, N_SRC, false><<<(N_DST1 * T * 4) / 256, 256, 0, stream>>>(
        off1, s_srt1, w_srt1, el1, er1, hs1, h1, wl2, wr2, el2, er2);
    k_gat<N_DST2, N_DST1, true><<<(N_DST2 * T * 4) / 256, 256, 0, stream>>>(
        off2, s_srt2, w_srt2, el2, er2, h1, out, W2, nullptr, nullptr, nullptr);
}